// Round 1
// baseline (115.587 us; speedup 1.0000x reference)
//
#include <hip/hip_runtime.h>
#include <math.h>

#define BOUNDF 10.0f
#define EPSF 1e-6f
#define MIN_SCALEF 1e-4f
#define DD 1024
#define KK 64
#define KP1 65

#define TD 16        // dims per block
#define NCELL 256    // uniform search-seed grid cells per dim (bytes in LDS)
#define TR 256       // rows per block (64 rows/pass * 4 passes)
#define ITER (TR / 64)

// softplus robust to large |x|, fast-math transcendentals
__device__ __forceinline__ float softplus_f(float x) {
    return fmaxf(x, 0.0f) + __logf(1.0f + __expf(-fabsf(x)));
}

// ---------------------------------------------------------------------------
// Fused kernel: each block builds spline tables for its 16 dims in LDS
// (softmax+cumsum via wave shuffles), then transforms a 16-dim x 256-row tile.
// Search = O(1) uniform-grid seed (byte LDS) + monotone fixup (~1-2 reads).
// Interval data packed {x0, y0, 1/w, h} -> single ds_read_b128 per element.
// LDS: 16*64*16 + 2*16*65*4 + 16*256 = 28.8 KB -> 5 blocks/CU (20 waves).
// ---------------------------------------------------------------------------
__global__ __launch_bounds__(256, 5) void rqs_fused(
    const float* __restrict__ u, const float* __restrict__ tau,
    const float* __restrict__ log_scale, const float* __restrict__ bias,
    const float* __restrict__ raw_w, const float* __restrict__ raw_h,
    const float* __restrict__ raw_s, float* __restrict__ out)
{
    __shared__ float4 livt[TD * KK];           // {x0, y0, invw, h} per interval
    __shared__ float  lxk[TD * KP1];           // knot x positions (search)
    __shared__ float  lsl[TD * KP1];           // softplus slopes
    __shared__ unsigned char lgr[TD * NCELL];  // bucket seed: bin of cell start

    const int bx = blockIdx.x;
    const int dchunk = bx & (DD / TD - 1);     // fast index -> concurrent blocks
    const int rchunk = bx >> 6;                //  cover full rows (streaming)
    const int d0 = dchunk * TD;
    const int r0 = rchunk * TR;
    const int t = threadIdx.x;
    const int wv = t >> 6;                     // wave 0..3
    const int lane = t & 63;

    // ---- phase 1: build tables, 4 dims per wave, lane <-> knot ----
    for (int jd = 0; jd < 4; ++jd) {
        const int dl = wv * 4 + jd;
        const int d = d0 + dl;
        float ew = __expf(raw_w[d * KK + lane]);
        float eh = __expf(raw_h[d * KK + lane]);
        float sw = ew, sh = eh;
#pragma unroll
        for (int off = 1; off < 64; off <<= 1) {
            sw += __shfl_xor(sw, off, 64);
            sh += __shfl_xor(sh, off, 64);
        }
        float wk = ew * ((2.0f * BOUNDF) / sw);    // width_k
        float hk = eh * ((2.0f * BOUNDF) / sh);    // height_k
        float cw = wk, ch = hk;                    // inclusive prefix sums
#pragma unroll
        for (int off = 1; off < 64; off <<= 1) {
            float aw = __shfl_up(cw, off, 64);
            float ah = __shfl_up(ch, off, 64);
            if (lane >= off) { cw += aw; ch += ah; }
        }
        // exclusive prefix via shfl: bit-exact match with neighbor lane's
        // inclusive prefix (guarantees gap-free grid partition below)
        float cwp = __shfl_up(cw, 1, 64); if (lane == 0) cwp = 0.0f;
        float chp = __shfl_up(ch, 1, 64); if (lane == 0) chp = 0.0f;
        float X  = -BOUNDF + cwp;
        float Yv = -BOUNDF + chp;
        float Xn = (lane == 63) ? BOUNDF : (-BOUNDF + cw);   // force top knot
        float Yn = (lane == 63) ? BOUNDF : (-BOUNDF + ch);   //  exactly (10,10)
        float invw = 1.0f / (Xn - X);
        livt[dl * KK + lane] = make_float4(X, Yv, invw, Yn - Yv);
        lxk[dl * KP1 + lane] = X;
        lsl[dl * KP1 + lane] = softplus_f(raw_s[d * KP1 + lane]);
        if (lane == 63) {
            lxk[dl * KP1 + 64] = BOUNDF;            // exact upper sentinel
            lsl[dl * KP1 + 64] = softplus_f(raw_s[d * KP1 + 64]);
        }
        // grid: lane k owns cells whose start z_c lies in [X_k, X_{k+1}).
        // c0(k) and c1(k-1) evaluate ceil() of the SAME float -> exact partition.
        int c0 = (int)ceilf(cwp * (NCELL / (2.0f * BOUNDF)));
        int c1 = (lane == 63) ? NCELL
                              : (int)ceilf(cw * (NCELL / (2.0f * BOUNDF)));
        c1 = min(c1, NCELL);
        for (int c = c0; c < c1; ++c) lgr[dl * NCELL + c] = (unsigned char)lane;
    }
    __syncthreads();

    // ---- phase 2: transform.  thread t -> dims 4*(t&3).., row (t>>2) ----
    const int g4 = (t & 3) * 4;
    const int rl = t >> 2;
    const int dg = d0 + g4;

    float sc[4], bi[4];
#pragma unroll
    for (int j = 0; j < 4; ++j) {
        sc[j] = softplus_f(log_scale[dg + j]) + MIN_SCALEF;
        bi[j] = bias[dg + j];
    }

    int b = r0 + rl;
    float4 uu = *(const float4*)(u + (size_t)b * DD + dg);
    float tb = tau[b];

#pragma unroll 1
    for (int it = 0; it < ITER; ++it) {
        const float4 ucur = uu;
        const float tcur = tb;
        const int bcur = b;
        if (it + 1 < ITER) {                     // software pipeline next load
            b += 64;
            uu = *(const float4*)(u + (size_t)b * DD + dg);
            tb = tau[b];
        }
        float ua[4] = {ucur.x, ucur.y, ucur.z, ucur.w};
        float res[4];
#pragma unroll
        for (int j = 0; j < 4; ++j) {
            float uv = fminf(fmaxf(ua[j], EPSF), 1.0f - EPSF);
            float z = __logf(uv * __builtin_amdgcn_rcpf(1.0f - uv));
            // cap just below +10 so the fixup loop terminates at lo=63
            float zc = fminf(fmaxf(z, -BOUNDF), 9.9999990f);
            const int bxk = (g4 + j) * KP1;
            int cell = (int)fmaf(zc, NCELL / (2.0f * BOUNDF), 0.5f * NCELL);
            int lo = (int)lgr[(g4 + j) * NCELL + cell];   // seed <= true bin
            float nx = lxk[bxk + lo + 1];
            bool adv = (nx <= zc);
            while (__any(adv)) {                 // avg ~1-2 iterations
                lo += adv;
                nx = lxk[bxk + lo + 1];
                adv = adv && (nx <= zc);
            }
            float4 iv = livt[(g4 + j) * KK + lo];  // one ds_read_b128
            float dd0 = lsl[bxk + lo];             // ds_read2_b32 pair
            float dd1 = lsl[bxk + lo + 1];
            float th  = (zc - iv.x) * iv.z;
            float s   = iv.w * iv.z;               // h/w
            float t1m = th * (1.0f - th);
            float den = fmaf(fmaf(-2.0f, s, dd0 + dd1), t1m, s);
            float num = iv.w * fmaf(s * th, th, dd0 * t1m);
            float y = fmaf(num, __builtin_amdgcn_rcpf(den), iv.y);
            y = (fabsf(z) < BOUNDF) ? y : z;       // passthrough outside
            res[j] = tcur * fmaf(y, sc[j], bi[j]);
        }
        *(float4*)(out + (size_t)bcur * DD + dg) =
            make_float4(res[0], res[1], res[2], res[3]);
    }
}

// ---------------------------------------------------------------------------
extern "C" void kernel_launch(void* const* d_in, const int* in_sizes, int n_in,
                              void* d_out, int out_size, void* d_ws, size_t ws_size,
                              hipStream_t stream)
{
    const float* u         = (const float*)d_in[0];
    const float* tau       = (const float*)d_in[1];
    const float* log_scale = (const float*)d_in[2];
    const float* bias      = (const float*)d_in[3];
    const float* raw_w     = (const float*)d_in[4];
    const float* raw_h     = (const float*)d_in[5];
    const float* raw_s     = (const float*)d_in[6];
    float* out = (float*)d_out;

    const int B = in_sizes[0] / DD;              // 8192
    rqs_fused<<<(DD / TD) * (B / TR), 256, 0, stream>>>(
        u, tau, log_scale, bias, raw_w, raw_h, raw_s, out);
}

// Round 2
// 109.670 us; speedup vs baseline: 1.0540x; 1.0540x over previous
//
#include <hip/hip_runtime.h>
#include <math.h>

#define BOUNDF 10.0f
#define EPSF 1e-6f
#define MIN_SCALEF 1e-4f
#define DD 1024
#define KK 64
#define KP1 65

#define TD 16        // dims per block (main)
#define NCELL 256    // uniform search-seed cells per dim
#define TR 512       // rows per block -> grid = 64*16 = 1024 = 4 blocks/CU exact
#define ITER (TR / 64)
#define CPB (NCELL / (2.0f * BOUNDF))   // cells per unit z = 12.8

// softplus robust to large |x|
__device__ __forceinline__ float softplus_f(float x) {
    return fmaxf(x, 0.0f) + __logf(1.0f + __expf(-fabsf(x)));
}

// ---------------------------------------------------------------------------
// Kernel 1: one block (1 wave) per dim.  Emits PACKED tables:
//   ivt (D,65) float4 {x0, y0, 1/w, h}   (entry 64 = {10,10,0,0} sentinel)
//   sl  (D,65) softplus slopes
//   grid(D,256) bytes: interval index containing each cell's start
//   scale (D)  softplus(log_scale)+MIN_SCALE
// ---------------------------------------------------------------------------
__global__ __launch_bounds__(64) void rqs_precompute(
    const float* __restrict__ raw_w, const float* __restrict__ raw_h,
    const float* __restrict__ raw_s, const float* __restrict__ log_scale,
    float4* __restrict__ ivt_g, float* __restrict__ sl_g,
    unsigned char* __restrict__ grid_g, float* __restrict__ scale_g)
{
    const int d = blockIdx.x;
    const int k = threadIdx.x;  // 0..63

    float ew = __expf(raw_w[d * KK + k]);
    float eh = __expf(raw_h[d * KK + k]);
    float sw = ew, sh = eh;
#pragma unroll
    for (int off = 1; off < 64; off <<= 1) {
        sw += __shfl_xor(sw, off, 64);
        sh += __shfl_xor(sh, off, 64);
    }
    float wk = ew * ((2.0f * BOUNDF) / sw);
    float hk = eh * ((2.0f * BOUNDF) / sh);
    float cw = wk, ch = hk;                    // inclusive prefix sums
#pragma unroll
    for (int off = 1; off < 64; off <<= 1) {
        float aw = __shfl_up(cw, off, 64);
        float ah = __shfl_up(ch, off, 64);
        if (k >= off) { cw += aw; ch += ah; }
    }
    // exclusive prefix = neighbor's inclusive prefix (bit-exact -> gap-free grid)
    float cwp = __shfl_up(cw, 1, 64); if (k == 0) cwp = 0.0f;
    float chp = __shfl_up(ch, 1, 64); if (k == 0) chp = 0.0f;
    float X  = -BOUNDF + cwp;
    float Yv = -BOUNDF + chp;
    float Xn = (k == 63) ? BOUNDF : (-BOUNDF + cw);
    float Yn = (k == 63) ? BOUNDF : (-BOUNDF + ch);
    ivt_g[d * KP1 + k] = make_float4(X, Yv, 1.0f / (Xn - X), Yn - Yv);
    sl_g[d * KP1 + k] = softplus_f(raw_s[d * KP1 + k]);
    if (k == 63) {
        ivt_g[d * KP1 + 64] = make_float4(BOUNDF, BOUNDF, 0.0f, 0.0f);
    }
    if (k == 0) {
        sl_g[d * KP1 + 64] = softplus_f(raw_s[d * KP1 + KK]);
        scale_g[d] = softplus_f(log_scale[d]) + MIN_SCALEF;
    }
    // grid: lane k owns cells whose start lies in [X_k, X_{k+1}).
    // c0(k) and c1(k-1) are ceil() of the SAME float -> exact partition.
    int c0 = (int)ceilf(cwp * CPB);
    int c1 = (k == 63) ? NCELL : (int)ceilf(cw * CPB);
    c1 = min(c1, NCELL);
    for (int c = c0; c < c1; ++c) grid_g[d * NCELL + c] = (unsigned char)k;
}

// ---------------------------------------------------------------------------
// Kernel 2: transform.  Block = 256 threads, tile = 16 dims x 512 rows.
// Phase 1 = pure coalesced LDS copy of packed tables (~25 KB, L2-hit).
// Phase 2: O(1) grid seed + monotone fixup; one ds_read_b128 per element
// for {x0,y0,1/w,h}; slopes via ds_read2.  LDS 24.4 KB, 4 blocks/CU.
// ---------------------------------------------------------------------------
__global__ __launch_bounds__(256, 4) void rqs_main(
    const float* __restrict__ u, const float* __restrict__ tau,
    const float* __restrict__ bias,
    const float4* __restrict__ ivt_g, const float* __restrict__ sl_g,
    const unsigned char* __restrict__ grid_g, const float* __restrict__ scale_g,
    float* __restrict__ out)
{
    __shared__ float4 livt[TD * KP1];          // 16.25 KB
    __shared__ float  lsl[TD * KP1];           //  4.06 KB
    __shared__ unsigned char lgr[TD * NCELL];  //  4.00 KB

    const int bx = blockIdx.x;
    const int dchunk = bx & (DD / TD - 1);     // fast idx -> concurrent blocks
    const int rchunk = bx >> 6;                //  cover full rows (streaming)
    const int d0 = dchunk * TD;
    const int r0 = rchunk * TR;
    const int t = threadIdx.x;

    // ---- phase 1: stage packed tables (coalesced) ----
    for (int i = t; i < TD * KP1; i += 256) {
        livt[i] = ivt_g[d0 * KP1 + i];
        lsl[i]  = sl_g[d0 * KP1 + i];
    }
    {
        const unsigned int* gsrc = (const unsigned int*)(grid_g + d0 * NCELL);
        unsigned int* gdst = (unsigned int*)lgr;
        for (int i = t; i < TD * NCELL / 4; i += 256) gdst[i] = gsrc[i];
    }
    __syncthreads();

    // ---- phase 2: thread t -> dims 4*(t&3).., row r0 + (t>>2) ----
    const int g4 = (t & 3) * 4;
    const int rl = t >> 2;
    const int dg = d0 + g4;

    float sc[4], bi[4];
#pragma unroll
    for (int j = 0; j < 4; ++j) {
        sc[j] = scale_g[dg + j];
        bi[j] = bias[dg + j];
    }

    int b = r0 + rl;
    float4 uu = *(const float4*)(u + (size_t)b * DD + dg);
    float tb = tau[b];

#pragma unroll 1
    for (int it = 0; it < ITER; ++it) {
        const float4 ucur = uu;
        const float tcur = tb;
        const int bcur = b;
        if (it + 1 < ITER) {                   // software pipeline next load
            b += 64;
            uu = *(const float4*)(u + (size_t)b * DD + dg);
            tb = tau[b];
        }
        float ua[4] = {ucur.x, ucur.y, ucur.z, ucur.w};
        float res[4];
#pragma unroll
        for (int j = 0; j < 4; ++j) {
            float uv = fminf(fmaxf(ua[j], EPSF), 1.0f - EPSF);
            float z = __logf(uv * __builtin_amdgcn_rcpf(1.0f - uv));
            // cap just below +10 so fixup terminates at lo=63 (sentinel x=10)
            float zc = fminf(fmaxf(z, -BOUNDF), 9.9999990f);
            const int ib = (g4 + j) * KP1;
            int cell = (int)fmaf(zc, CPB, 0.5f * NCELL);
            int lo = (int)lgr[(g4 + j) * NCELL + cell];   // seed <= true bin
            float nx = livt[ib + lo + 1].x;
            bool adv = (nx <= zc);
            while (__any(adv)) {               // avg ~1 whole-wave iteration
                lo += adv;
                nx = livt[ib + lo + 1].x;
                adv = adv && (nx <= zc);
            }
            float4 iv = livt[ib + lo];         // one ds_read_b128
            float dd0 = lsl[ib + lo];          // ds_read2_b32 pair
            float dd1 = lsl[ib + lo + 1];
            float th  = (zc - iv.x) * iv.z;
            float s   = iv.w * iv.z;           // h/w
            float t1m = th * (1.0f - th);
            float den = fmaf(fmaf(-2.0f, s, dd0 + dd1), t1m, s);
            float num = iv.w * fmaf(s * th, th, dd0 * t1m);
            float y = fmaf(num, __builtin_amdgcn_rcpf(den), iv.y);
            y = (fabsf(z) < BOUNDF) ? y : z;   // passthrough outside
            res[j] = tcur * fmaf(y, sc[j], bi[j]);
        }
        *(float4*)(out + (size_t)bcur * DD + dg) =
            make_float4(res[0], res[1], res[2], res[3]);
    }
}

// ---------------------------------------------------------------------------
extern "C" void kernel_launch(void* const* d_in, const int* in_sizes, int n_in,
                              void* d_out, int out_size, void* d_ws, size_t ws_size,
                              hipStream_t stream)
{
    const float* u         = (const float*)d_in[0];
    const float* tau       = (const float*)d_in[1];
    const float* log_scale = (const float*)d_in[2];
    const float* bias      = (const float*)d_in[3];
    const float* raw_w     = (const float*)d_in[4];
    const float* raw_h     = (const float*)d_in[5];
    const float* raw_s     = (const float*)d_in[6];
    float* out = (float*)d_out;

    // workspace layout (needs ~1.6 MB)
    float* ws = (float*)d_ws;
    float4* ivt = (float4*)ws;                               // D*65 float4
    float* sl = ws + (size_t)DD * KP1 * 4;                   // D*65 floats
    unsigned char* grid = (unsigned char*)(sl + DD * KP1);   // D*256 bytes
    float* scale = (float*)(grid + (size_t)DD * NCELL);      // D floats

    const int B = in_sizes[0] / DD;                          // 8192

    rqs_precompute<<<DD, 64, 0, stream>>>(raw_w, raw_h, raw_s, log_scale,
                                          ivt, sl, grid, scale);
    rqs_main<<<(DD / TD) * (B / TR), 256, 0, stream>>>(
        u, tau, bias, ivt, sl, grid, scale, out);
}